// Round 15
// baseline (178.370 us; speedup 1.0000x reference)
//
#include <hip/hip_runtime.h>
#include <hip/hip_bf16.h>

// ---------------------------------------------------------------------------
// QLayer: per-type 2-layer MLP.
//   h   = relu(x_t @ W1_t + b1_t)       [16384x512]@[512x1024]   (x4 types)
//   out = h @ W2_t + b2_t, padded to 128 cols                    (x4 types)
// Round 15: GEMM1 stages A as RAW FP32 via global_load_lds (no cvt_x pass,
// no fa-register path) and converts fp32->bf16 on LDS read, just before the
// MFMA. Full 160KB LDS: A-fp32 dbuf 2x64KB (latency hidden, tile-early GLDs)
// + B bf16 single 32KB (L2-resident W1T, restaged between a barrier pair).
// Convert VALU overlaps the MFMA pipe (m114); r9's fa path (~1850 cyc/tile
// of load->VALU->ds_write) and the 30us cvt_x dispatch both disappear.
// ---------------------------------------------------------------------------

typedef __attribute__((ext_vector_type(8))) short short8;
typedef __attribute__((ext_vector_type(4))) float f32x4;

#define NT 4
#define NNODE 16384
#define DIN 512
#define DH 1024
#define MAXO 128

static __device__ __forceinline__ ushort f2bf(float f) {
    __hip_bfloat16 h = __float2bfloat16(f);
    return *reinterpret_cast<ushort*>(&h);
}

static __device__ __forceinline__ short8 pack8(const float4 a, const float4 b) {
    union { short8 v; ushort u[8]; } r;
    r.u[0] = f2bf(a.x); r.u[1] = f2bf(a.y); r.u[2] = f2bf(a.z); r.u[3] = f2bf(a.w);
    r.u[4] = f2bf(b.x); r.u[5] = f2bf(b.y); r.u[6] = f2bf(b.z); r.u[7] = f2bf(b.w);
    return r.v;
}

#define GLD(gsrc, ldst)                                                        \
    __builtin_amdgcn_global_load_lds(                                          \
        (const __attribute__((address_space(1))) void*)(gsrc),                 \
        (__attribute__((address_space(3))) void*)(ldst), 16, 0, 0)

// --- W1 transpose+convert: in fp32 [R][Cin] -> out bf16 [Cout][R] ----------
__global__ __launch_bounds__(256) void cvt_w_t_kernel(
    const float* __restrict__ in, ushort* __restrict__ out,
    int R, int Cin, size_t in_tstride, size_t out_tstride) {
    __shared__ float tile[32][33];
    const int t = blockIdx.z;
    in += (size_t)t * in_tstride;
    out += (size_t)t * out_tstride;
    const int c0 = blockIdx.x * 32, r0 = blockIdx.y * 32;
    const int cx = threadIdx.x & 31;
    const int ry = threadIdx.x >> 5;   // 0..7
#pragma unroll
    for (int j = 0; j < 4; ++j) {
        int rr = ry + j * 8;
        int c = c0 + cx;
        tile[rr][cx] = (c < Cin) ? in[(size_t)(r0 + rr) * Cin + c] : 0.0f;
    }
    __syncthreads();
#pragma unroll
    for (int j = 0; j < 4; ++j) {
        int cc = ry + j * 8;
        out[(size_t)(c0 + cc) * R + r0 + cx] = f2bf(tile[cx][cc]);
    }
}

// --- W2 (all 4 types) transpose+convert + b2 pad, one launch ---------------
__global__ __launch_bounds__(256) void cvt_w2_kernel(
    const float* __restrict__ w0, const float* __restrict__ w1,
    const float* __restrict__ w2, const float* __restrict__ w3,
    const float* __restrict__ c0_, const float* __restrict__ c1_,
    const float* __restrict__ c2_, const float* __restrict__ c3_,
    ushort* __restrict__ out, float* __restrict__ b2p) {
    __shared__ float tile[32][33];
    const int t = blockIdx.z;
    const int Cin = (t == 0) ? 128 : (t == 1) ? 96 : (t == 2) ? 64 : 32;
    const float* in = (t == 0) ? w0 : (t == 1) ? w1 : (t == 2) ? w2 : w3;
    ushort* o = out + (size_t)t * MAXO * DH;
    const int c0 = blockIdx.x * 32, r0 = blockIdx.y * 32;
    const int cx = threadIdx.x & 31;
    const int ry = threadIdx.x >> 5;
#pragma unroll
    for (int j = 0; j < 4; ++j) {
        int rr = ry + j * 8;
        int c = c0 + cx;
        tile[rr][cx] = (c < Cin) ? in[(size_t)(r0 + rr) * Cin + c] : 0.0f;
    }
    __syncthreads();
#pragma unroll
    for (int j = 0; j < 4; ++j) {
        int cc = ry + j * 8;
        o[(size_t)(c0 + cc) * DH + r0 + cx] = f2bf(tile[cx][cc]);
    }
    if (blockIdx.x == 0 && blockIdx.y == 0 && threadIdx.x < 128) {
        const float* b = (t == 0) ? c0_ : (t == 1) ? c1_ : (t == 2) ? c2_ : c3_;
        const int n = threadIdx.x;
        b2p[t * 128 + n] = (n < Cin) ? b[n] : 0.0f;
    }
}

// ---------------------------------------------------------------------------
// GEMM1: H = relu(X @ W1 + b1). BM=256, BN=256, BK=64, 512 thr = 8 waves
// (2x4), wave tile 128x64, acc[8][4]=128 AGPR.
// LDS (160KB): A-fp32 dbuf 2x[256r][64k f32] (64KB each, 256B rows) @0,
//              B-bf16 single [256r][64k] (32KB, 128B rows) @131072.
// XOR swizzle both: chunk16B' = chunk16B ^ (row&7)  (== byte ^ ((r&7)<<4)).
//
// Per K-tile i:
//   issue 8 GLD A-f32(i+1) -> Abuf[(i+1)&1]   (a full tile to land)
//   compute: 2 kkk x { 4 B-frag ds_read_b128;
//                      8 x (2 ds_read_b128 f32 + pack8 -> bf16 A-frag);
//                      32 MFMA }
//   barrier (Bbuf consumed) ; issue 4 GLD B(i+1) -> Bbuf ;
//   vmcnt(0) [A(i+1)+B(i+1) landed; A loads are ~1 tile old] ; barrier
// MFMA operands swapped (D-row dim = n) -> vectorized bf16 epilogue stores.
// Grid 1024 = 4t x 64m x 4n (n fastest), XCD-bijective swizzle.
// ---------------------------------------------------------------------------
__global__ __launch_bounds__(512, 1) void gemm1r(
    const float* __restrict__ x0, const float* __restrict__ x1,
    const float* __restrict__ x2, const float* __restrict__ x3,
    const ushort* __restrict__ W1T, const float* __restrict__ b1,
    ushort* __restrict__ H) {
    constexpr int K = DIN;                 // 512
    __shared__ char lds[163840];           // A0 @0, A1 @65536, B @131072

    // XCD-bijective block swizzle (grid 1024 % 8 == 0)
    const int cpx = gridDim.x >> 3;
    const int g = blockIdx.x;
    const int wg = (g & 7) * cpx + (g >> 3);
    const int t = wg >> 8;                 // 256 tiles per type
    const int rmn = wg & 255;
    const int m0 = (rmn >> 2) * 256;       // 64 m-tiles
    const int n0 = (rmn & 3) * 256;        // 4 n-tiles (fastest: X L2 reuse)

    const float* Af = (t == 0) ? x0 : (t == 1) ? x1 : (t == 2) ? x2 : x3;
    const ushort* Bp = W1T + (size_t)t * DH * K;
    const float* bias = b1 + (size_t)t * DH;
    ushort* Ht = H + (size_t)t * NNODE * DH;

    const int tid = threadIdx.x;
    const int lane = tid & 63;
    const int w = tid >> 6;
    const int wm = w >> 2, wn = w & 3;     // WM=2, WN=4
    const int lrow = lane & 15, lgrp = lane >> 4;

    // A fp32 staging: 8 chunks/thread (64KB / 16B / 512 thr)
    const float* asrc[8];
    int adst[8];
#pragma unroll
    for (int j = 0; j < 8; ++j) {
        const int c = j * 512 + tid;       // chunk 0..4095
        const int r = c >> 4;              // row 0..255 (16 chunks/row)
        const int cb = ((c & 15) * 16) ^ ((r & 7) << 4);   // swizzled src byte
        asrc[j] = Af + (size_t)(m0 + r) * K + (cb >> 2);
        adst[j] = c * 16;                  // linear dst for global_load_lds
    }
    // B bf16 staging: 4 chunks/thread (32KB / 16B / 512 thr)
    const ushort* bsrc[4];
    int bdst[4];
#pragma unroll
    for (int j = 0; j < 4; ++j) {
        const int c = j * 512 + tid;       // chunk 0..2047
        const int r = c >> 3;              // row 0..255 (8 chunks/row)
        const int cb = ((c & 7) * 16) ^ ((r & 7) << 4);
        bsrc[j] = Bp + (size_t)(n0 + r) * K + (cb >> 1);
        bdst[j] = 131072 + c * 16;
    }

    f32x4 acc[8][4] = {};
    const int NK = K / 64;                 // 8

    // --- prologue: A(0)->buf0, B(0) ---------------------------------------
#pragma unroll
    for (int j = 0; j < 8; ++j) GLD(asrc[j], lds + adst[j]);
#pragma unroll
    for (int j = 0; j < 4; ++j) GLD(bsrc[j], lds + bdst[j]);
    asm volatile("s_waitcnt vmcnt(0)" ::: "memory");
    __builtin_amdgcn_s_barrier();
    asm volatile("" ::: "memory");

    for (int i = 0; i < NK; ++i) {
        const char* Al = lds + (i & 1) * 65536;
        const bool more = (i + 1 < NK);

        // issue A(i+1) fp32 GLDs into the other buffer (lands during compute)
        if (more) {
            const int ofs = (i + 1) * 64;  // float offset
            char* An = lds + ((i + 1) & 1) * 65536;
#pragma unroll
            for (int j = 0; j < 8; ++j) GLD(asrc[j] + ofs, An + adst[j]);
        }

        // ---- compute tile i ----
#pragma unroll
        for (int kkk = 0; kkk < 2; ++kkk) {
            short8 bfr[4], af[8];
#pragma unroll
            for (int ni = 0; ni < 4; ++ni) {
                const int br = wn * 64 + ni * 16 + lrow;
                const int kb = (kkk * 64 + lgrp * 16) ^ ((br & 7) << 4);
                bfr[ni] = *(const short8*)(lds + 131072 + br * 128 + kb);
            }
#pragma unroll
            for (int ml = 0; ml < 8; ++ml) {
                const int ar = wm * 128 + ml * 16 + lrow;
                const int base = kkk * 128 + lgrp * 32;
                const int sw = (ar & 7) << 4;
                const float4 lo = *(const float4*)(Al + ar * 256 + (base ^ sw));
                const float4 hi = *(const float4*)(Al + ar * 256 + ((base + 16) ^ sw));
                af[ml] = pack8(lo, hi);     // fp32 -> bf16 on read (RNE)
            }
#pragma unroll
            for (int ml = 0; ml < 8; ++ml)
#pragma unroll
                for (int ni = 0; ni < 4; ++ni)
                    acc[ml][ni] = __builtin_amdgcn_mfma_f32_16x16x32_bf16(
                        bfr[ni], af[ml], acc[ml][ni], 0, 0, 0);
        }

        if (more) {
            // Bbuf fully consumed by all waves -> safe to restage
            asm volatile("" ::: "memory");
            __builtin_amdgcn_s_barrier();
            asm volatile("" ::: "memory");
            const int ofs = (i + 1) * 64;  // bf16 elem offset
#pragma unroll
            for (int j = 0; j < 4; ++j) GLD(bsrc[j] + ofs, lds + bdst[j]);
            // A(i+1) loads are ~1 tile old -> cheap; B is L2-resident W1T
            asm volatile("s_waitcnt vmcnt(0)" ::: "memory");
            __builtin_amdgcn_s_barrier();
            asm volatile("" ::: "memory");
        }
    }

    // --- epilogue (swapped operands): lane holds 4 consecutive n at reg r --
    // m = wmoff + mi*16 + lrow ; n = wnoff + ni*16 + lgrp*4 + r
    const int wnoff = n0 + wn * 64;
    const int wmoff = m0 + wm * 128;
#pragma unroll
    for (int ni = 0; ni < 4; ++ni) {
        const int ncol = wnoff + ni * 16 + lgrp * 4;
        const float4 bv = *reinterpret_cast<const float4*>(&bias[ncol]);
#pragma unroll
        for (int mi = 0; mi < 8; ++mi) {
            const int row = wmoff + mi * 16 + lrow;
            float v0 = fmaxf(acc[mi][ni][0] + bv.x, 0.0f);
            float v1 = fmaxf(acc[mi][ni][1] + bv.y, 0.0f);
            float v2 = fmaxf(acc[mi][ni][2] + bv.z, 0.0f);
            float v3 = fmaxf(acc[mi][ni][3] + bv.w, 0.0f);
            uint2 p;
            p.x = (uint)f2bf(v0) | ((uint)f2bf(v1) << 16);
            p.y = (uint)f2bf(v2) | ((uint)f2bf(v3) << 16);
            *reinterpret_cast<uint2*>(&Ht[(size_t)row * DH + ncol]) = p;
        }
    }
}

// ---------------------------------------------------------------------------
// GEMM2 (r9/r11 dbuf structure, at HBM floor): out = H @ W2T^T + b2.
// BM=256, BN=128, BK=64 dbuf, 1 barrier/K-tile, GLD staging, XOR swizzle.
// ---------------------------------------------------------------------------
__global__ __launch_bounds__(512, 1) void gemm2k(
    const ushort* __restrict__ Hbase, const ushort* __restrict__ Bbase,
    const float* __restrict__ biasbase, float* __restrict__ Cbase,
    int N, int K, int MT) {
    constexpr int NF = 2;                  // BN=128
    constexpr int NBC = 2;
    constexpr int ABYTES = 256 * 64 * 2;   // 32 KB
    constexpr int BBYTES = 128 * 64 * 2;   // 16 KB
    constexpr int BUF = ABYTES + BBYTES;
    __shared__ char lds[2 * BUF];

    const int cpx = gridDim.x >> 3;
    const int g = blockIdx.x;
    const int wg = (g & 7) * cpx + (g >> 3);
    const int t = wg / MT;
    const int m0 = (wg % MT) * 256;

    const ushort* A = Hbase + (size_t)t * NNODE * DH;
    const ushort* Bp = Bbase + (size_t)t * MAXO * DH;
    const float* bias = biasbase + (size_t)t * MAXO;

    const int tid = threadIdx.x;
    const int lane = tid & 63;
    const int w = tid >> 6;
    const int wm = w >> 2, wn = w & 3;
    const int lrow = lane & 15, lgrp = lane >> 4;

    const ushort* abfsrc[4];
    int adst[4];
#pragma unroll
    for (int j = 0; j < 4; ++j) {
        const int c = j * 512 + tid;
        const int r = c >> 3;
        const int cb = ((c & 7) * 16) ^ ((r & 7) << 4);
        abfsrc[j] = A + (size_t)(m0 + r) * K + (cb >> 1);
        adst[j] = c * 16;
    }
    const ushort* bsrc[NBC];
    int bdst[NBC];
#pragma unroll
    for (int j = 0; j < NBC; ++j) {
        const int c = j * 512 + tid;
        const int r = c >> 3;
        const int cb = ((c & 7) * 16) ^ ((r & 7) << 4);
        bsrc[j] = Bp + (size_t)r * K + (cb >> 1);
        bdst[j] = ABYTES + c * 16;
    }

    f32x4 acc[8][NF] = {};
    const int NK = K / 64;

#pragma unroll
    for (int j = 0; j < 4; ++j) GLD(abfsrc[j], lds + adst[j]);
#pragma unroll
    for (int j = 0; j < NBC; ++j) GLD(bsrc[j], lds + bdst[j]);
    asm volatile("s_waitcnt vmcnt(0)" ::: "memory");
    __builtin_amdgcn_s_barrier();
    asm volatile("" ::: "memory");

    for (int i = 0; i < NK; ++i) {
        const char* cu_ = lds + (i & 1) * BUF;
        char* nx_ = lds + ((i + 1) & 1) * BUF;
        const int ktn = (i + 1) * 64;
        const bool st = (i + 1 < NK);

        if (st) {
#pragma unroll
            for (int j = 0; j < 4; ++j) GLD(abfsrc[j] + ktn, nx_ + adst[j]);
#pragma unroll
            for (int j = 0; j < NBC; ++j) GLD(bsrc[j] + ktn, nx_ + bdst[j]);
        }

#pragma unroll
        for (int kkk = 0; kkk < 2; ++kkk) {
            short8 bfr[NF], af[8];
#pragma unroll
            for (int ni = 0; ni < NF; ++ni) {
                const int br = wn * (NF * 16) + ni * 16 + lrow;
                const int kb = (kkk * 64 + lgrp * 16) ^ ((br & 7) << 4);
                bfr[ni] = *(const short8*)(cu_ + ABYTES + br * 128 + kb);
            }
#pragma unroll
            for (int ml = 0; ml < 8; ++ml) {
                const int ar = wm * 128 + ml * 16 + lrow;
                const int kb = (kkk * 64 + lgrp * 16) ^ ((ar & 7) << 4);
                af[ml] = *(const short8*)(cu_ + ar * 128 + kb);
            }
#pragma unroll
            for (int ml = 0; ml < 8; ++ml)
#pragma unroll
                for (int ni = 0; ni < NF; ++ni)
                    acc[ml][ni] = __builtin_amdgcn_mfma_f32_16x16x32_bf16(
                        bfr[ni], af[ml], acc[ml][ni], 0, 0, 0);
        }

        if (st) {
            asm volatile("s_waitcnt vmcnt(0)" ::: "memory");
            __builtin_amdgcn_s_barrier();
            asm volatile("" ::: "memory");
        }
    }

    const int wnoff = wn * (NF * 16);
    const int wmoff = m0 + wm * 128;
#pragma unroll
    for (int ni = 0; ni < NF; ++ni) {
        const int ncol = wnoff + ni * 16 + lgrp * 4;
        const float4 bv = *reinterpret_cast<const float4*>(&bias[ncol]);
#pragma unroll
        for (int mi = 0; mi < 8; ++mi) {
            const int row = wmoff + mi * 16 + lrow;
            float4 p;
            p.x = acc[mi][ni][0] + bv.x;
            p.y = acc[mi][ni][1] + bv.y;
            p.z = acc[mi][ni][2] + bv.z;
            p.w = acc[mi][ni][3] + bv.w;
            *reinterpret_cast<float4*>(
                &Cbase[(size_t)t * NNODE * MAXO + (size_t)row * N + ncol]) = p;
        }
    }
}

extern "C" void kernel_launch(void* const* d_in, const int* in_sizes, int n_in,
                              void* d_out, int out_size, void* d_ws, size_t ws_size,
                              hipStream_t stream) {
    const float* x0 = (const float*)d_in[0];
    const float* x1 = (const float*)d_in[1];
    const float* x2 = (const float*)d_in[2];
    const float* x3 = (const float*)d_in[3];
    // d_in[4] = node_type (unused: nodes are blocked by type already)
    const float* W1 = (const float*)d_in[5];
    const float* b1 = (const float*)d_in[6];
    const float* W2[4] = {(const float*)d_in[7], (const float*)d_in[9],
                          (const float*)d_in[11], (const float*)d_in[13]};
    const float* b2[4] = {(const float*)d_in[8], (const float*)d_in[10],
                          (const float*)d_in[12], (const float*)d_in[14]};

    // workspace layout (bytes):
    //   H    bf16 [4][16384][1024]  134217728
    //   W1T  bf16 [4][1024][512]      4194304
    //   W2T  bf16 [4][128][1024]      1048576
    //   b2p  f32  [4][128]                2048
    char* ws = (char*)d_ws;
    ushort* H   = (ushort*)ws;
    ushort* W1T = (ushort*)(ws + 134217728ull);
    ushort* W2T = (ushort*)(ws + 134217728ull + 4194304ull);
    float*  b2p = (float*)(ws + 134217728ull + 4194304ull + 1048576ull);

    // weight conversions (small)
    cvt_w_t_kernel<<<dim3(32, 16, 4), 256, 0, stream>>>(
        W1, W1T, DIN, DH, (size_t)DIN * DH, (size_t)DH * DIN);
    cvt_w2_kernel<<<dim3(4, 32, 4), 256, 0, stream>>>(
        W2[0], W2[1], W2[2], W2[3], b2[0], b2[1], b2[2], b2[3], W2T, b2p);

    // layer 1: H = relu(X @ W1 + b1); A staged fp32, converted on LDS read
    // grid: 4 types x 64 m-tiles x 4 n-tiles = 1024 (n fastest)
    gemm1r<<<1024, 512, 0, stream>>>(x0, x1, x2, x3, W1T, b1, H);

    // layer 2: out = H @ W2 + b2 (padded cols exactly 0), fp32 out
    // grid: 4 types x 64 m-tiles = 256
    gemm2k<<<256, 512, 0, stream>>>(H, W2T, b2p, (float*)d_out,
                                    MAXO, DH, NNODE / 256);
}

// Round 16
// 153.987 us; speedup vs baseline: 1.1583x; 1.1583x over previous
//
#include <hip/hip_runtime.h>
#include <hip/hip_bf16.h>

// ---------------------------------------------------------------------------
// QLayer: per-type 2-layer MLP.
//   h   = relu(x_t @ W1_t + b1_t)       [16384x512]@[512x1024]   (x4 types)
//   out = h @ W2_t + b2_t, padded to 128 cols                    (x4 types)
// FINAL (= round-9 measured best, 153.4us): 256-tile 1-barrier-per-K-tile
// GEMM with the fp32->bf16 X conversion fused into GEMM1's A path via a
// 1-tile-deep register pipeline (fa holds tile i+1's X during tile i;
// ds_write at tile top overlaps frag reads; refill gets 2 tiles of latency;
// counted vmcnt(8) keeps refills in flight across barriers - T4).
// GEMM2 at its HBM floor (~21us). T1 XCD swizzle + T2 LDS XOR swizzle.
//
// Session constraint note: at K=512 (8 BK=64 tiles) the 128-reg accumulator
// + ~108 arch regs pin every big-tile config at 2 waves/SIMD (RF = 512
// unified/SIMD, thresholds measured r13/r14), so cross-block overlap is
// unreachable and ~26% MfmaUtil is the practical ceiling of this shape;
// smaller tiles trade reuse for occupancy at a net loss (r13/r14).
// ---------------------------------------------------------------------------

typedef __attribute__((ext_vector_type(8))) short short8;
typedef __attribute__((ext_vector_type(4))) float f32x4;

#define NT 4
#define NNODE 16384
#define DIN 512
#define DH 1024
#define MAXO 128

static __device__ __forceinline__ ushort f2bf(float f) {
    __hip_bfloat16 h = __float2bfloat16(f);
    return *reinterpret_cast<ushort*>(&h);
}

static __device__ __forceinline__ short8 pack8(const float4 a, const float4 b) {
    union { short8 v; ushort u[8]; } r;
    r.u[0] = f2bf(a.x); r.u[1] = f2bf(a.y); r.u[2] = f2bf(a.z); r.u[3] = f2bf(a.w);
    r.u[4] = f2bf(b.x); r.u[5] = f2bf(b.y); r.u[6] = f2bf(b.z); r.u[7] = f2bf(b.w);
    return r.v;
}

#define GLD(gsrc, ldst)                                                        \
    __builtin_amdgcn_global_load_lds(                                          \
        (const __attribute__((address_space(1))) void*)(gsrc),                 \
        (__attribute__((address_space(3))) void*)(ldst), 16, 0, 0)

// --- W1 transpose+convert: in fp32 [R][Cin] -> out bf16 [Cout][R] ----------
__global__ __launch_bounds__(256) void cvt_w_t_kernel(
    const float* __restrict__ in, ushort* __restrict__ out,
    int R, int Cin, size_t in_tstride, size_t out_tstride) {
    __shared__ float tile[32][33];
    const int t = blockIdx.z;
    in += (size_t)t * in_tstride;
    out += (size_t)t * out_tstride;
    const int c0 = blockIdx.x * 32, r0 = blockIdx.y * 32;
    const int cx = threadIdx.x & 31;
    const int ry = threadIdx.x >> 5;   // 0..7
#pragma unroll
    for (int j = 0; j < 4; ++j) {
        int rr = ry + j * 8;
        int c = c0 + cx;
        tile[rr][cx] = (c < Cin) ? in[(size_t)(r0 + rr) * Cin + c] : 0.0f;
    }
    __syncthreads();
#pragma unroll
    for (int j = 0; j < 4; ++j) {
        int cc = ry + j * 8;
        out[(size_t)(c0 + cc) * R + r0 + cx] = f2bf(tile[cx][cc]);
    }
}

// --- W2 (all 4 types) transpose+convert + b2 pad, one launch ---------------
// grid: (4, 32, 4); per t: in fp32 [DH][osz_t] -> out bf16 [128][DH] (rows
// >= osz_t are zero); block (0,0,t) threads 0..127 also pad b2.
__global__ __launch_bounds__(256) void cvt_w2_kernel(
    const float* __restrict__ w0, const float* __restrict__ w1,
    const float* __restrict__ w2, const float* __restrict__ w3,
    const float* __restrict__ c0_, const float* __restrict__ c1_,
    const float* __restrict__ c2_, const float* __restrict__ c3_,
    ushort* __restrict__ out, float* __restrict__ b2p) {
    __shared__ float tile[32][33];
    const int t = blockIdx.z;
    const int Cin = (t == 0) ? 128 : (t == 1) ? 96 : (t == 2) ? 64 : 32;
    const float* in = (t == 0) ? w0 : (t == 1) ? w1 : (t == 2) ? w2 : w3;
    ushort* o = out + (size_t)t * MAXO * DH;
    const int c0 = blockIdx.x * 32, r0 = blockIdx.y * 32;
    const int cx = threadIdx.x & 31;
    const int ry = threadIdx.x >> 5;
#pragma unroll
    for (int j = 0; j < 4; ++j) {
        int rr = ry + j * 8;
        int c = c0 + cx;
        tile[rr][cx] = (c < Cin) ? in[(size_t)(r0 + rr) * Cin + c] : 0.0f;
    }
    __syncthreads();
#pragma unroll
    for (int j = 0; j < 4; ++j) {
        int cc = ry + j * 8;
        o[(size_t)(c0 + cc) * DH + r0 + cx] = f2bf(tile[cx][cc]);
    }
    if (blockIdx.x == 0 && blockIdx.y == 0 && threadIdx.x < 128) {
        const float* b = (t == 0) ? c0_ : (t == 1) ? c1_ : (t == 2) ? c2_ : c3_;
        const int n = threadIdx.x;
        b2p[t * 128 + n] = (n < Cin) ? b[n] : 0.0f;
    }
}

// ---------------------------------------------------------------------------
// 1-barrier-per-tile 256-tile bf16 GEMM: C = A[M][K] * BT[N][K]^T + bias
// BM=256, BN in {256,128}, BK=64, 512 threads = 8 waves (WM=2, WN=4).
// Wave tile 128 x (BN/4). LDS: dbuf x (A 32KB + B), XOR-swizzle both sides:
// byte(row,col16) = row*128 + ((col16*16) ^ ((row&7)<<4)).
//
// A path, AFP32=1 (x inputs, fused fp32->bf16), 1-tile-deep reg pipeline:
//   invariant: entering tile i, fa regs hold X data of K-tile i+1.
//   tile top: [B GLDs (oldest)] [pack8+ds_write fa -> next buf]
//             [refill fa with tile i+2 (newest, 2 tiles to land)]
//   tile end: s_waitcnt vmcnt(8) (retire B; fa stays in flight) lgkmcnt(0).
// A path, AFP32=0 (H bf16): global_load_lds w16, pre-swizzled src.
// B path: always bf16 global_load_lds w16, pre-swizzled src, linear dst.
// MFMA operands swapped (D-row dim = n) -> vectorized epilogue stores.
// ---------------------------------------------------------------------------
template <int BN, bool AFP32, bool RELU, bool OUTBF16>
__global__ __launch_bounds__(512, 1) void gemmf(
    const void* __restrict__ A0, const void* __restrict__ A1,
    const void* __restrict__ A2, const void* __restrict__ A3,
    const ushort* __restrict__ Bbase, const float* __restrict__ biasbase,
    void* __restrict__ Cbase, int N, int K, int MT,
    size_t strideA, size_t strideB, size_t strideBias, size_t strideC) {
    constexpr int NF = BN / 64;            // N-frags per wave (4 or 2)
    constexpr int NBC = BN * 8 / 512;      // B chunks per thread (4 or 2)
    constexpr int ABYTES = 256 * 64 * 2;   // 32 KB
    constexpr int BBYTES = BN * 64 * 2;    // 32 or 16 KB
    constexpr int BUF = ABYTES + BBYTES;
    __shared__ char lds[2 * BUF];
    static_assert(!AFP32 || NBC == 4, "AFP32 path assumes BN=256");

    // XCD-bijective block swizzle (grid % 8 == 0 by construction)
    const int cpx = gridDim.x >> 3;
    const int g = blockIdx.x;
    const int wg = (g & 7) * cpx + (g >> 3);
    const int NTL = N / BN;
    const int t = wg / (MT * NTL);
    const int rmn = wg % (MT * NTL);
    const int m0 = (rmn / NTL) * 256;
    const int n0 = (rmn % NTL) * BN;

    const float* Af = (const float*)((t == 0) ? A0 : (t == 1) ? A1
                                   : (t == 2) ? A2 : A3);        // AFP32
    const ushort* Ab = (const ushort*)A0 + (size_t)t * strideA;  // !AFP32
    const ushort* Bp = Bbase + (size_t)t * strideB;
    const float* bias = biasbase + (size_t)t * strideBias;

    const int tid = threadIdx.x;
    const int lane = tid & 63;
    const int w = tid >> 6;
    const int wm = w >> 2, wn = w & 3;     // WM=2, WN=4
    const int lrow = lane & 15, lgrp = lane >> 4;

    // --- staging addresses: 4 A chunks + NBC B chunks per thread -----------
    const float* af32src[4];               // AFP32: linear f32 src
    const ushort* abfsrc[4];               // !AFP32: pre-swizzled bf16 src
    int adst[4];                           // AFP32: swizzled dst; else linear
#pragma unroll
    for (int j = 0; j < 4; ++j) {
        const int c = j * 512 + tid;       // chunk 0..2047
        const int r = c >> 3;              // A row 0..255
        const int c8 = c & 7;
        const int cb = (c8 * 16) ^ ((r & 7) << 4);
        if (AFP32) {
            af32src[j] = Af + (size_t)(m0 + r) * K + c8 * 8;
            adst[j] = r * 128 + cb;        // swizzled dst for ds_write_b128
        } else {
            abfsrc[j] = Ab + (size_t)(m0 + r) * K + (cb >> 1);
            adst[j] = c * 16;              // linear dst for global_load_lds
        }
    }
    const ushort* bsrc[NBC];
    int bdst[NBC];
#pragma unroll
    for (int j = 0; j < NBC; ++j) {
        const int c = j * 512 + tid;       // chunk 0..BN*8-1
        const int r = c >> 3;              // B row 0..BN-1
        const int cb = ((c & 7) * 16) ^ ((r & 7) << 4);
        bsrc[j] = Bp + (size_t)(n0 + r) * K + (cb >> 1);
        bdst[j] = ABYTES + c * 16;
    }

    f32x4 acc[8][NF] = {};
    const int NK = K / 64;
    float4 fa[4][2];                       // fp32 A regs (AFP32 path)

    // --- prologue ----------------------------------------------------------
    if (AFP32) {
        // fa <- tile 0
#pragma unroll
        for (int j = 0; j < 4; ++j) {
            fa[j][0] = *reinterpret_cast<const float4*>(af32src[j]);
            fa[j][1] = *reinterpret_cast<const float4*>(af32src[j] + 4);
        }
#pragma unroll
        for (int j = 0; j < NBC; ++j) GLD(bsrc[j], lds + bdst[j]);
        asm volatile("s_waitcnt vmcnt(4)" ::: "memory");   // fa0 landed
#pragma unroll
        for (int j = 0; j < 4; ++j)
            *reinterpret_cast<short8*>(lds + adst[j]) = pack8(fa[j][0], fa[j][1]);
        asm volatile("" ::: "memory");
        if (NK > 1) {
            // fa <- tile 1 (entering loop, fa holds tile i+1 = 1)
#pragma unroll
            for (int j = 0; j < 4; ++j) {
                fa[j][0] = *reinterpret_cast<const float4*>(af32src[j] + 64);
                fa[j][1] = *reinterpret_cast<const float4*>(af32src[j] + 68);
            }
        }
        asm volatile("s_waitcnt vmcnt(8) lgkmcnt(0)" ::: "memory"); // B0 done
    } else {
#pragma unroll
        for (int j = 0; j < 4; ++j) GLD(abfsrc[j], lds + adst[j]);
#pragma unroll
        for (int j = 0; j < NBC; ++j) GLD(bsrc[j], lds + bdst[j]);
        asm volatile("s_waitcnt vmcnt(0) lgkmcnt(0)" ::: "memory");
    }
    __builtin_amdgcn_s_barrier();
    asm volatile("" ::: "memory");

    for (int i = 0; i < NK; ++i) {
        const char* cu_ = lds + (i & 1) * BUF;
        char* nx_ = lds + ((i + 1) & 1) * BUF;
        const int ktn = (i + 1) * 64;
        const bool st = (i + 1 < NK);
        const bool st2 = (i + 2 < NK);

        if (st) {
#pragma unroll
            for (int j = 0; j < NBC; ++j) GLD(bsrc[j] + ktn, nx_ + bdst[j]);
            if (AFP32) {
                // publish fa (tile i+1 data, loaded a full tile ago)
#pragma unroll
                for (int j = 0; j < 4; ++j)
                    *reinterpret_cast<short8*>(nx_ + adst[j]) =
                        pack8(fa[j][0], fa[j][1]);
                asm volatile("" ::: "memory");   // keep refill below writes
                if (st2) {
#pragma unroll
                    for (int j = 0; j < 4; ++j) {
                        fa[j][0] = *reinterpret_cast<const float4*>(
                            af32src[j] + ktn + 64);
                        fa[j][1] = *reinterpret_cast<const float4*>(
                            af32src[j] + ktn + 68);
                    }
                }
            } else {
#pragma unroll
                for (int j = 0; j < 4; ++j) GLD(abfsrc[j] + ktn, nx_ + adst[j]);
            }
        }

#pragma unroll
        for (int kkk = 0; kkk < 2; ++kkk) {
            short8 bfr[NF], af[8];
#pragma unroll
            for (int ni = 0; ni < NF; ++ni) {
                const int br = wn * (NF * 16) + ni * 16 + lrow;
                const int kb = (kkk * 64 + lgrp * 16) ^ ((br & 7) << 4);
                bfr[ni] = *(const short8*)(cu_ + ABYTES + br * 128 + kb);
            }
#pragma unroll
            for (int ml = 0; ml < 8; ++ml) {
                const int ar = wm * 128 + ml * 16 + lrow;
                const int kb = (kkk * 64 + lgrp * 16) ^ ((ar & 7) << 4);
                af[ml] = *(const short8*)(cu_ + ar * 128 + kb);
            }
#pragma unroll
            for (int ml = 0; ml < 8; ++ml)
#pragma unroll
                for (int ni = 0; ni < NF; ++ni)
                    acc[ml][ni] = __builtin_amdgcn_mfma_f32_16x16x32_bf16(
                        bfr[ni], af[ml], acc[ml][ni], 0, 0, 0);
        }

        if (st) {
            // counted wait: retire B(i+1) [+A GLDs on !AFP32]; on AFP32 the
            // 8 fa refill loads (newest) STAY in flight across the barrier.
            if (AFP32 && st2)
                asm volatile("s_waitcnt vmcnt(8) lgkmcnt(0)" ::: "memory");
            else
                asm volatile("s_waitcnt vmcnt(0) lgkmcnt(0)" ::: "memory");
            __builtin_amdgcn_s_barrier();
            asm volatile("" ::: "memory");
        }
    }

    // --- epilogue (swapped operands): lane holds 4 consecutive n at reg r --
    // m = wmoff + mi*16 + lrow ; n = wnoff + ni*16 + lgrp*4 + r
    const int wnoff = n0 + wn * (NF * 16);
    const int wmoff = m0 + wm * 128;
#pragma unroll
    for (int ni = 0; ni < NF; ++ni) {
        const int ncol = wnoff + ni * 16 + lgrp * 4;
        const float4 bv = *reinterpret_cast<const float4*>(&bias[ncol]);
#pragma unroll
        for (int mi = 0; mi < 8; ++mi) {
            const int row = wmoff + mi * 16 + lrow;
            float v0 = acc[mi][ni][0] + bv.x;
            float v1 = acc[mi][ni][1] + bv.y;
            float v2 = acc[mi][ni][2] + bv.z;
            float v3 = acc[mi][ni][3] + bv.w;
            if (RELU) {
                v0 = fmaxf(v0, 0.0f); v1 = fmaxf(v1, 0.0f);
                v2 = fmaxf(v2, 0.0f); v3 = fmaxf(v3, 0.0f);
            }
            const size_t base = (size_t)t * strideC + (size_t)row * N + ncol;
            if (OUTBF16) {
                uint2 p;
                p.x = (uint)f2bf(v0) | ((uint)f2bf(v1) << 16);
                p.y = (uint)f2bf(v2) | ((uint)f2bf(v3) << 16);
                *reinterpret_cast<uint2*>(&((ushort*)Cbase)[base]) = p;
            } else {
                float4 p = {v0, v1, v2, v3};
                *reinterpret_cast<float4*>(&((float*)Cbase)[base]) = p;
            }
        }
    }
}

extern "C" void kernel_launch(void* const* d_in, const int* in_sizes, int n_in,
                              void* d_out, int out_size, void* d_ws, size_t ws_size,
                              hipStream_t stream) {
    const float* x0 = (const float*)d_in[0];
    const float* x1 = (const float*)d_in[1];
    const float* x2 = (const float*)d_in[2];
    const float* x3 = (const float*)d_in[3];
    // d_in[4] = node_type (unused: nodes are blocked by type already)
    const float* W1 = (const float*)d_in[5];
    const float* b1 = (const float*)d_in[6];
    const float* W2[4] = {(const float*)d_in[7], (const float*)d_in[9],
                          (const float*)d_in[11], (const float*)d_in[13]};
    const float* b2[4] = {(const float*)d_in[8], (const float*)d_in[10],
                          (const float*)d_in[12], (const float*)d_in[14]};

    // workspace layout (bytes):
    //   H    bf16 [4][16384][1024]  134217728
    //   W1T  bf16 [4][1024][512]      4194304
    //   W2T  bf16 [4][128][1024]      1048576
    //   b2p  f32  [4][128]                2048
    char* ws = (char*)d_ws;
    ushort* H   = (ushort*)ws;
    ushort* W1T = (ushort*)(ws + 134217728ull);
    ushort* W2T = (ushort*)(ws + 134217728ull + 4194304ull);
    float*  b2p = (float*)(ws + 134217728ull + 4194304ull + 1048576ull);

    // weight conversions (small)
    cvt_w_t_kernel<<<dim3(32, 16, 4), 256, 0, stream>>>(
        W1, W1T, DIN, DH, (size_t)DIN * DH, (size_t)DH * DIN);
    cvt_w2_kernel<<<dim3(4, 32, 4), 256, 0, stream>>>(
        W2[0], W2[1], W2[2], W2[3], b2[0], b2[1], b2[2], b2[3], W2T, b2p);

    // layer 1: H = relu(X @ W1 + b1), fused fp32->bf16 A path, bf16 out
    // grid: 4 types x 64 m-tiles x 4 n-tiles = 1024 (n fastest: A L2 reuse)
    gemmf<256, true, true, true><<<1024, 512, 0, stream>>>(
        x0, x1, x2, x3, W1T, b1, H,
        DH, DIN, NNODE / 256,
        0, (size_t)DH * DIN, (size_t)DH, (size_t)NNODE * DH);

    // layer 2: out = H @ W2 + b2 (padded cols exactly 0), fp32 out
    // grid: 4 types x 64 m-tiles x 1 n-tile = 256
    gemmf<128, false, false, false><<<256, 512, 0, stream>>>(
        H, H, H, H, W2T, b2p, d_out,
        MAXO, DH, NNODE / 256,
        (size_t)NNODE * DH, (size_t)MAXO * DH, (size_t)MAXO,
        (size_t)NNODE * MAXO);
}